// Round 10
// baseline (511.032 us; speedup 1.0000x reference)
//
#include <hip/hip_runtime.h>
#include <hip/hip_bf16.h>
#include <hip/hip_fp16.h>

#define HID 128
#define N_GRAPHS 64

// ---------------------------------------------------------------------------
// 1) degree init (self-loop counts as 1)
__global__ void init_deg_kernel(int* __restrict__ deg, int n) {
    int i = blockIdx.x * 256 + threadIdx.x;
    if (i < n) deg[i] = 1;
}

// 2) count in-degrees
__global__ void count_kernel(const int* __restrict__ dst, int* __restrict__ deg, int E) {
    int e = blockIdx.x * 256 + threadIdx.x;
    if (e < E) atomicAdd(&deg[dst[e]], 1);
}

// 3a) per-block partial sums of deg
__global__ __launch_bounds__(256) void scan_partial_kernel(const int* __restrict__ deg,
                                                           int* __restrict__ bsum, int n) {
    __shared__ int red[256];
    int t = threadIdx.x;
    int i = blockIdx.x * 256 + t;
    red[t] = (i < n) ? deg[i] : 0;
    __syncthreads();
#pragma unroll
    for (int s = 128; s > 0; s >>= 1) {
        if (t < s) red[t] += red[t + s];
        __syncthreads();
    }
    if (t == 0) bsum[blockIdx.x] = red[0];
}

// 3b) single-block exclusive scan of block sums (nb <= 256)
__global__ __launch_bounds__(256) void scan_bsum_kernel(const int* __restrict__ bsum,
                                                        int* __restrict__ boff,
                                                        int* __restrict__ row_ptr,
                                                        int nb, int n) {
    __shared__ int arr[256];
    int t = threadIdx.x;
    int own = (t < nb) ? bsum[t] : 0;
    arr[t] = own;
    __syncthreads();
#pragma unroll
    for (int off = 1; off < 256; off <<= 1) {
        int v = arr[t];
        int add = (t >= off) ? arr[t - off] : 0;
        __syncthreads();
        arr[t] = v + add;
        __syncthreads();
    }
    if (t < nb) boff[t] = arr[t] - own;
    if (t == 255) row_ptr[n] = arr[255];
}

// 3c) emit row_ptr/cursor/dinv
__global__ __launch_bounds__(256) void scan_emit_kernel(const int* __restrict__ deg,
                                                        const int* __restrict__ boff,
                                                        int* __restrict__ row_ptr,
                                                        int* __restrict__ cursor,
                                                        float* __restrict__ dinv, int n) {
    __shared__ int arr[256];
    int t = threadIdx.x;
    int i = blockIdx.x * 256 + t;
    int d = (i < n) ? deg[i] : 0;
    arr[t] = d;
    __syncthreads();
#pragma unroll
    for (int off = 1; off < 256; off <<= 1) {
        int v = arr[t];
        int add = (t >= off) ? arr[t - off] : 0;
        __syncthreads();
        arr[t] = v + add;
        __syncthreads();
    }
    if (i < n) {
        int pos = boff[blockIdx.x] + arr[t] - d;
        row_ptr[i] = pos;
        cursor[i] = pos;
        dinv[i] = rsqrtf((float)d);
    }
}

// 4) fill CSR columns (edges + implicit self-loops)
__global__ void fill_kernel(const int* __restrict__ src, const int* __restrict__ dst,
                            int* __restrict__ cursor, int* __restrict__ col,
                            int E, int EN) {
    int e = blockIdx.x * 256 + threadIdx.x;
    if (e >= EN) return;
    int s, d;
    if (e < E) { s = src[e]; d = dst[e]; }
    else       { s = e - E; d = s; }
    int pos = atomicAdd(&cursor[d], 1);
    col[pos] = s;
}

// 5) GEMM: hw16[r][:] = fp16( dinv[r] * (A[r][:] @ W) )
//    64x128 tile, 8x4 per thread, BK=32, double-buffered LDS:
//    next chunk's global loads issued into regs BEFORE computing current chunk.
__global__ __launch_bounds__(256) void gemm_scale_kernel(const float* __restrict__ A,
                                                         const float* __restrict__ W,
                                                         const float* __restrict__ dinv,
                                                         __half* __restrict__ out16, int M) {
    __shared__ float sAT[2][32][68];    // [buf][k][row]  2 x 8.5 KB
    __shared__ float sW [2][32][132];   // [buf][k][col]  2 x 16.5 KB
    int tid = threadIdx.x;
    int row0 = blockIdx.x * 64;
    int ty = tid >> 5, tx = tid & 31;   // ty 0..7, tx 0..31
    int r0 = ty * 8;
    int j0 = tx * 4;

    float acc[8][4];
#pragma unroll
    for (int i = 0; i < 8; ++i)
#pragma unroll
        for (int j = 0; j < 4; ++j) acc[i][j] = 0.f;

    // ---- stage chunk 0 into buf 0 ----
#pragma unroll
    for (int p = 0; p < 4; ++p) {               // W: 32x128 floats
        int idx = tid + p * 256;
        int k = idx >> 5, c4 = idx & 31;
        *(float4*)&sW[0][k][c4 * 4] = *(const float4*)(W + (size_t)k * 128 + c4 * 4);
    }
#pragma unroll
    for (int p = 0; p < 2; ++p) {               // A: 64x32 floats, transposed
        int idx = tid + p * 256;
        int r = idx >> 3, c4 = idx & 7;
        float4 v = make_float4(0.f, 0.f, 0.f, 0.f);
        if (row0 + r < M) v = *(const float4*)(A + (size_t)(row0 + r) * 128 + c4 * 4);
        sAT[0][c4 * 4 + 0][r] = v.x;
        sAT[0][c4 * 4 + 1][r] = v.y;
        sAT[0][c4 * 4 + 2][r] = v.z;
        sAT[0][c4 * 4 + 3][r] = v.w;
    }
    __syncthreads();

    for (int kci = 0; kci < 4; ++kci) {
        int cur = kci & 1;
        float4 wreg[4], areg[2];
        if (kci < 3) {                          // issue next chunk's loads (latency hides under compute)
            int kc = (kci + 1) * 32;
#pragma unroll
            for (int p = 0; p < 4; ++p) {
                int idx = tid + p * 256;
                int k = idx >> 5, c4 = idx & 31;
                wreg[p] = *(const float4*)(W + (size_t)(kc + k) * 128 + c4 * 4);
            }
#pragma unroll
            for (int p = 0; p < 2; ++p) {
                int idx = tid + p * 256;
                int r = idx >> 3, c4 = idx & 7;
                areg[p] = make_float4(0.f, 0.f, 0.f, 0.f);
                if (row0 + r < M) areg[p] = *(const float4*)(A + (size_t)(row0 + r) * 128 + kc + c4 * 4);
            }
        }

        // ---- compute current chunk ----
#pragma unroll 4
        for (int k = 0; k < 32; ++k) {
            float4 a0 = *(float4*)&sAT[cur][k][r0];
            float4 a1 = *(float4*)&sAT[cur][k][r0 + 4];
            float4 w4 = *(float4*)&sW[cur][k][j0];
            float a[8] = {a0.x, a0.y, a0.z, a0.w, a1.x, a1.y, a1.z, a1.w};
#pragma unroll
            for (int i = 0; i < 8; ++i) {
                acc[i][0] += a[i] * w4.x;
                acc[i][1] += a[i] * w4.y;
                acc[i][2] += a[i] * w4.z;
                acc[i][3] += a[i] * w4.w;
            }
        }
        __syncthreads();                        // all reads of buf^1 (from kci-1) long done; cur reads done

        if (kci < 3) {                          // write staged regs into other buffer
            int nbuf = cur ^ 1;
#pragma unroll
            for (int p = 0; p < 4; ++p) {
                int idx = tid + p * 256;
                int k = idx >> 5, c4 = idx & 31;
                *(float4*)&sW[nbuf][k][c4 * 4] = wreg[p];
            }
#pragma unroll
            for (int p = 0; p < 2; ++p) {
                int idx = tid + p * 256;
                int r = idx >> 3, c4 = idx & 7;
                sAT[nbuf][c4 * 4 + 0][r] = areg[p].x;
                sAT[nbuf][c4 * 4 + 1][r] = areg[p].y;
                sAT[nbuf][c4 * 4 + 2][r] = areg[p].z;
                sAT[nbuf][c4 * 4 + 3][r] = areg[p].w;
            }
            __syncthreads();
        }
    }

    // ---- epilogue: scale by dinv, convert fp16, store ----
#pragma unroll
    for (int i = 0; i < 8; ++i) {
        int r = row0 + r0 + i;
        if (r < M) {
            float dv = dinv[r];
            __half2 h0 = __floats2half2_rn(acc[i][0] * dv, acc[i][1] * dv);
            __half2 h1 = __floats2half2_rn(acc[i][2] * dv, acc[i][3] * dv);
            float2 pk;
            ((__half2*)&pk)[0] = h0; ((__half2*)&pk)[1] = h1;
            *(float2*)(out16 + (size_t)r * 128 + j0) = pk;
        }
    }
}

// 6) aggregation: out[v][:] = relu(dinv[v] * sum_{s in N(v)} hw16[s][:] + b)
//    16 lanes per node, float4 (8 halfs) per lane; fp32 accumulate; 4-deep unroll.
__global__ __launch_bounds__(256) void aggregate_kernel(const __half* __restrict__ hw,
                                                        const int* __restrict__ row_ptr,
                                                        const int* __restrict__ col,
                                                        const float* __restrict__ dinv,
                                                        const float* __restrict__ bias,
                                                        float* __restrict__ out, int n) {
    int tid = threadIdx.x;
    int v = blockIdx.x * 16 + (tid >> 4);
    if (v >= n) return;
    int j = (tid & 15) * 8;                    // half index
    int p0 = row_ptr[v], p1 = row_ptr[v + 1];
    float acc[8];
#pragma unroll
    for (int q = 0; q < 8; ++q) acc[q] = 0.f;

    int p = p0;
    for (; p + 3 < p1; p += 4) {
        int s0 = col[p], s1 = col[p + 1], s2 = col[p + 2], s3 = col[p + 3];
        float4 r0 = *(const float4*)(hw + (size_t)s0 * 128 + j);
        float4 r1 = *(const float4*)(hw + (size_t)s1 * 128 + j);
        float4 r2 = *(const float4*)(hw + (size_t)s2 * 128 + j);
        float4 r3 = *(const float4*)(hw + (size_t)s3 * 128 + j);
        const __half2* h0 = (const __half2*)&r0;
        const __half2* h1 = (const __half2*)&r1;
        const __half2* h2 = (const __half2*)&r2;
        const __half2* h3 = (const __half2*)&r3;
#pragma unroll
        for (int q = 0; q < 4; ++q) {
            float2 f0 = __half22float2(h0[q]);
            float2 f1 = __half22float2(h1[q]);
            float2 f2 = __half22float2(h2[q]);
            float2 f3 = __half22float2(h3[q]);
            acc[2 * q + 0] += (f0.x + f1.x) + (f2.x + f3.x);
            acc[2 * q + 1] += (f0.y + f1.y) + (f2.y + f3.y);
        }
    }
    for (; p < p1; ++p) {
        int s0 = col[p];
        float4 r0 = *(const float4*)(hw + (size_t)s0 * 128 + j);
        const __half2* h0 = (const __half2*)&r0;
#pragma unroll
        for (int q = 0; q < 4; ++q) {
            float2 f0 = __half22float2(h0[q]);
            acc[2 * q + 0] += f0.x;
            acc[2 * q + 1] += f0.y;
        }
    }
    float dv = dinv[v];
    float4 bb0 = *(const float4*)(bias + j);
    float4 bb1 = *(const float4*)(bias + j + 4);
    float4 o0, o1;
    o0.x = fmaxf(acc[0] * dv + bb0.x, 0.f);
    o0.y = fmaxf(acc[1] * dv + bb0.y, 0.f);
    o0.z = fmaxf(acc[2] * dv + bb0.z, 0.f);
    o0.w = fmaxf(acc[3] * dv + bb0.w, 0.f);
    o1.x = fmaxf(acc[4] * dv + bb1.x, 0.f);
    o1.y = fmaxf(acc[5] * dv + bb1.y, 0.f);
    o1.z = fmaxf(acc[6] * dv + bb1.z, 0.f);
    o1.w = fmaxf(acc[7] * dv + bb1.w, 0.f);
    *(float4*)(out + (size_t)v * 128 + j) = o0;
    *(float4*)(out + (size_t)v * 128 + j + 4) = o1;
}

// 7) graph boundary detection (batch sorted)
__global__ void boundary_kernel(const int* __restrict__ batch, int* __restrict__ start, int n) {
    int i = blockIdx.x * 256 + threadIdx.x;
    if (i >= n) return;
    int b = batch[i];
    int pb = (i > 0) ? batch[i - 1] : -1;
    if (b != pb) {
        for (int g = pb + 1; g <= b; ++g) start[g] = i;
    }
    if (i == n - 1) {
        for (int g = b + 1; g <= N_GRAPHS; ++g) start[g] = n;
    }
}

// 8) pooled mean per graph
__global__ __launch_bounds__(256) void pool_reduce_kernel(const float* __restrict__ h,
                                                          const int* __restrict__ start,
                                                          float* __restrict__ pooled) {
    __shared__ float part[8][128];
    int g = blockIdx.x;
    int s = start[g], e = start[g + 1];
    int tid = threadIdx.x;
    int grp = tid >> 5;
    int j = (tid & 31) * 4;
    float4 acc = make_float4(0.f, 0.f, 0.f, 0.f);
    for (int v = s + grp; v < e; v += 8) {
        float4 a = *(const float4*)(h + (size_t)v * 128 + j);
        acc.x += a.x; acc.y += a.y; acc.z += a.z; acc.w += a.w;
    }
    *(float4*)&part[grp][j] = acc;
    __syncthreads();
    if (tid < 128) {
        float sum = 0.f;
#pragma unroll
        for (int k = 0; k < 8; ++k) sum += part[k][tid];
        int cntv = e - s; if (cntv < 1) cntv = 1;
        pooled[g * 128 + tid] = sum / (float)cntv;
    }
}

// 9) final MLP
__global__ __launch_bounds__(256) void mlp_kernel(const float* __restrict__ pooled_g,
                                                  const float* __restrict__ W1,
                                                  const float* __restrict__ b1,
                                                  const float* __restrict__ W2,
                                                  const float* __restrict__ b2,
                                                  float* __restrict__ out) {
    __shared__ float pooled[64][128];
    __shared__ float h1[64][64];
    int tid = threadIdx.x;
    for (int i = tid; i < 64 * 128; i += 256) pooled[i >> 7][i & 127] = pooled_g[i];
    __syncthreads();
    for (int i = tid; i < 64 * 64; i += 256) {
        int g = i >> 6, j = i & 63;
        float acc = b1[j];
        for (int k = 0; k < 128; ++k) acc += pooled[g][k] * W1[k * 64 + j];
        h1[g][j] = fmaxf(acc, 0.f);
    }
    __syncthreads();
    if (tid < 128) {
        int g = tid >> 1, c = tid & 1;
        float acc = b2[c];
        for (int jj = 0; jj < 64; ++jj) acc += h1[g][jj] * W2[jj * 2 + c];
        out[tid] = acc;
    }
}

// ---------------------------------------------------------------------------
extern "C" void kernel_launch(void* const* d_in, const int* in_sizes, int n_in,
                              void* d_out, int out_size, void* d_ws, size_t ws_size,
                              hipStream_t stream) {
    const float* x    = (const float*)d_in[0];
    const int*   ei   = (const int*)d_in[1];
    const int*   batch= (const int*)d_in[2];
    const float* W0   = (const float*)d_in[3];
    const float* b0   = (const float*)d_in[4];
    const float* Ws   = (const float*)d_in[5];
    const float* bs   = (const float*)d_in[6];
    const float* W1   = (const float*)d_in[7];
    const float* b1   = (const float*)d_in[8];
    const float* W2   = (const float*)d_in[9];
    const float* b2   = (const float*)d_in[10];
    float* out = (float*)d_out;

    const int n  = in_sizes[0] / HID;      // 50000
    const int E  = in_sizes[1] / 2;        // 800000
    const int EN = E + n;                  // 850000
    const int* src = ei;
    const int* dst = ei + E;
    const int nb = (n + 255) / 256;        // 196

    char* ws = (char*)d_ws;
    size_t off = 0;
    auto alloc = [&](size_t bytes) { void* p = ws + off; off = (off + bytes + 255) & ~(size_t)255; return p; };
    float*  bufA   = (float*) alloc((size_t)n * HID * 4);   // h (fp32)
    __half* hw16   = (__half*)alloc((size_t)n * HID * 2);   // gemm output (fp16)
    float*  dinv   = (float*) alloc((size_t)n * 4);
    int*    row_ptr= (int*)   alloc((size_t)(n + 1) * 4);
    int*    cursor = (int*)   alloc((size_t)n * 4);
    int*    deg    = (int*)   alloc((size_t)n * 4);
    int*    col    = (int*)   alloc((size_t)EN * 4);
    int*    bsum   = (int*)   alloc((size_t)nb * 4);
    int*    boff   = (int*)   alloc((size_t)nb * 4);
    int*    gstart = (int*)   alloc((N_GRAPHS + 1) * 4);
    float*  pooled = (float*) alloc(N_GRAPHS * 128 * 4);
    (void)ws_size; (void)n_in; (void)out_size;

    // --- build normalized CSR ---
    init_deg_kernel<<<nb, 256, 0, stream>>>(deg, n);
    count_kernel<<<(E + 255) / 256, 256, 0, stream>>>(dst, deg, E);
    scan_partial_kernel<<<nb, 256, 0, stream>>>(deg, bsum, n);
    scan_bsum_kernel<<<1, 256, 0, stream>>>(bsum, boff, row_ptr, nb, n);
    scan_emit_kernel<<<nb, 256, 0, stream>>>(deg, boff, row_ptr, cursor, dinv, n);
    fill_kernel<<<(EN + 255) / 256, 256, 0, stream>>>(src, dst, cursor, col, E, EN);
    boundary_kernel<<<nb, 256, 0, stream>>>(batch, gstart, n);

    const int gemm_grid = (n + 63) / 64;    // 782
    const int node_grid = (n + 15) / 16;    // 3125

    // --- layer 0 ---
    gemm_scale_kernel<<<gemm_grid, 256, 0, stream>>>(x, W0, dinv, hw16, n);
    aggregate_kernel<<<node_grid, 256, 0, stream>>>(hw16, row_ptr, col, dinv, b0, bufA, n);
    // --- layers 1..3 ---
    for (int l = 0; l < 3; ++l) {
        gemm_scale_kernel<<<gemm_grid, 256, 0, stream>>>(bufA, Ws + (size_t)l * HID * HID, dinv, hw16, n);
        aggregate_kernel<<<node_grid, 256, 0, stream>>>(hw16, row_ptr, col, dinv, bs + (size_t)l * HID, bufA, n);
    }

    // --- pooling + MLP ---
    pool_reduce_kernel<<<N_GRAPHS, 256, 0, stream>>>(bufA, gstart, pooled);
    mlp_kernel<<<1, 256, 0, stream>>>(pooled, W1, b1, W2, b2, out);
}

// Round 12
// 461.796 us; speedup vs baseline: 1.1066x; 1.1066x over previous
//
#include <hip/hip_runtime.h>
#include <hip/hip_bf16.h>
#include <hip/hip_fp16.h>

#define HID 128
#define N_GRAPHS 64

typedef _Float16 h8 __attribute__((ext_vector_type(8)));
typedef float f4 __attribute__((ext_vector_type(4)));

// ---------------------------------------------------------------------------
// 1) degree init (self-loop counts as 1)
__global__ void init_deg_kernel(int* __restrict__ deg, int n) {
    int i = blockIdx.x * 256 + threadIdx.x;
    if (i < n) deg[i] = 1;
}

// 2) count in-degrees
__global__ void count_kernel(const int* __restrict__ dst, int* __restrict__ deg, int E) {
    int e = blockIdx.x * 256 + threadIdx.x;
    if (e < E) atomicAdd(&deg[dst[e]], 1);
}

// 3a) per-block partial sums of deg
__global__ __launch_bounds__(256) void scan_partial_kernel(const int* __restrict__ deg,
                                                           int* __restrict__ bsum, int n) {
    __shared__ int red[256];
    int t = threadIdx.x;
    int i = blockIdx.x * 256 + t;
    red[t] = (i < n) ? deg[i] : 0;
    __syncthreads();
#pragma unroll
    for (int s = 128; s > 0; s >>= 1) {
        if (t < s) red[t] += red[t + s];
        __syncthreads();
    }
    if (t == 0) bsum[blockIdx.x] = red[0];
}

// 3b) single-block exclusive scan of block sums (nb <= 256)
__global__ __launch_bounds__(256) void scan_bsum_kernel(const int* __restrict__ bsum,
                                                        int* __restrict__ boff,
                                                        int* __restrict__ row_ptr,
                                                        int nb, int n) {
    __shared__ int arr[256];
    int t = threadIdx.x;
    int own = (t < nb) ? bsum[t] : 0;
    arr[t] = own;
    __syncthreads();
#pragma unroll
    for (int off = 1; off < 256; off <<= 1) {
        int v = arr[t];
        int add = (t >= off) ? arr[t - off] : 0;
        __syncthreads();
        arr[t] = v + add;
        __syncthreads();
    }
    if (t < nb) boff[t] = arr[t] - own;
    if (t == 255) row_ptr[n] = arr[255];
}

// 3c) emit row_ptr/cursor/dinv
__global__ __launch_bounds__(256) void scan_emit_kernel(const int* __restrict__ deg,
                                                        const int* __restrict__ boff,
                                                        int* __restrict__ row_ptr,
                                                        int* __restrict__ cursor,
                                                        float* __restrict__ dinv, int n) {
    __shared__ int arr[256];
    int t = threadIdx.x;
    int i = blockIdx.x * 256 + t;
    int d = (i < n) ? deg[i] : 0;
    arr[t] = d;
    __syncthreads();
#pragma unroll
    for (int off = 1; off < 256; off <<= 1) {
        int v = arr[t];
        int add = (t >= off) ? arr[t - off] : 0;
        __syncthreads();
        arr[t] = v + add;
        __syncthreads();
    }
    if (i < n) {
        int pos = boff[blockIdx.x] + arr[t] - d;
        row_ptr[i] = pos;
        cursor[i] = pos;
        dinv[i] = rsqrtf((float)d);
    }
}

// 4) fill CSR columns (edges + implicit self-loops)
__global__ void fill_kernel(const int* __restrict__ src, const int* __restrict__ dst,
                            int* __restrict__ cursor, int* __restrict__ col,
                            int E, int EN) {
    int e = blockIdx.x * 256 + threadIdx.x;
    if (e >= EN) return;
    int s, d;
    if (e < E) { s = src[e]; d = dst[e]; }
    else       { s = e - E; d = s; }
    int pos = atomicAdd(&cursor[d], 1);
    col[pos] = s;
}

// 4b) fp32 -> fp16 convert (8 elems/thread)
__global__ void cvt_kernel(const float* __restrict__ in, __half* __restrict__ out, int total8) {
    int i = blockIdx.x * 256 + threadIdx.x;
    if (i >= total8) return;
    float4 v0 = *(const float4*)(in + (size_t)i * 8);
    float4 v1 = *(const float4*)(in + (size_t)i * 8 + 4);
    __half2 p0 = __floats2half2_rn(v0.x, v0.y);
    __half2 p1 = __floats2half2_rn(v0.z, v0.w);
    __half2 p2 = __floats2half2_rn(v1.x, v1.y);
    __half2 p3 = __floats2half2_rn(v1.z, v1.w);
    float4 pk;
    ((__half2*)&pk)[0] = p0; ((__half2*)&pk)[1] = p1;
    ((__half2*)&pk)[2] = p2; ((__half2*)&pk)[3] = p3;
    *(float4*)(out + (size_t)i * 8) = pk;
}

// 5) MFMA GEMM: hw16[r][:] = fp16( dinv[r] * (A16[r][:] @ W) )
//    64 rows/block (4 waves x 16 rows), W^T staged fp16 in LDS [128][136]
//    (pad 136 -> 272B row stride -> 2-way banks = free).
//    A-frag: lane l holds A[row + (l&15)][8*(l>>4)..+7]  (one 16B global load)
//    C-frag (m89-verified): col = l&15, row = (l>>4)*4 + reg
__global__ __launch_bounds__(256) void gemm_mfma_kernel(const __half* __restrict__ A16,
                                                        const float* __restrict__ W,
                                                        const float* __restrict__ dinv,
                                                        __half* __restrict__ out16, int M) {
    __shared__ _Float16 sWt[128][136];
    int tid = threadIdx.x;
    for (int i = tid * 4; i < 128 * 128; i += 1024) {
        int k = i >> 7, nn = i & 127;
        float4 v = *(const float4*)(W + i);
        sWt[nn + 0][k] = (_Float16)v.x;
        sWt[nn + 1][k] = (_Float16)v.y;
        sWt[nn + 2][k] = (_Float16)v.z;
        sWt[nn + 3][k] = (_Float16)v.w;
    }
    __syncthreads();

    int wave = tid >> 6;
    int lane = tid & 63;
    int l15 = lane & 15;
    int kg = lane >> 4;                     // 0..3
    int rowb = blockIdx.x * 64 + wave * 16;
    int arow = rowb + l15;

    h8 zero;
#pragma unroll
    for (int q = 0; q < 8; ++q) zero[q] = (_Float16)0.f;

    h8 afrag[4];
    if (arow < M) {
        const h8* Av = (const h8*)(A16 + (size_t)arow * 128 + kg * 8);
#pragma unroll
        for (int kc = 0; kc < 4; ++kc) afrag[kc] = Av[kc * 4];  // +32 halves per chunk
    } else {
#pragma unroll
        for (int kc = 0; kc < 4; ++kc) afrag[kc] = zero;
    }

    int orow0 = rowb + kg * 4;              // C rows this lane owns
    float dv[4];
#pragma unroll
    for (int j = 0; j < 4; ++j)
        dv[j] = (orow0 + j < M) ? dinv[orow0 + j] : 0.f;

    for (int ct = 0; ct < 8; ++ct) {
        h8 bfrag[4];
#pragma unroll
        for (int kc = 0; kc < 4; ++kc)
            bfrag[kc] = *(const h8*)&sWt[ct * 16 + l15][kc * 32 + kg * 8];
        f4 acc = {0.f, 0.f, 0.f, 0.f};
#pragma unroll
        for (int kc = 0; kc < 4; ++kc)
            acc = __builtin_amdgcn_mfma_f32_16x16x32_f16(afrag[kc], bfrag[kc], acc, 0, 0, 0);
#pragma unroll
        for (int j = 0; j < 4; ++j) {
            int r = orow0 + j;
            if (r < M)
                out16[(size_t)r * 128 + ct * 16 + l15] = __float2half(acc[j] * dv[j]);
        }
    }
}

// 6) aggregation: h16[v][:] = fp16( relu(dinv[v] * sum_{s in N(v)} hw16[s][:] + b) )
//    16 lanes per node, 8 halfs per lane; fp32 accumulate; 4-deep unroll.
__global__ __launch_bounds__(256) void aggregate_kernel(const __half* __restrict__ hw,
                                                        const int* __restrict__ row_ptr,
                                                        const int* __restrict__ col,
                                                        const float* __restrict__ dinv,
                                                        const float* __restrict__ bias,
                                                        __half* __restrict__ out16, int n) {
    int tid = threadIdx.x;
    int v = blockIdx.x * 16 + (tid >> 4);
    if (v >= n) return;
    int j = (tid & 15) * 8;
    int p0 = row_ptr[v], p1 = row_ptr[v + 1];
    float acc[8];
#pragma unroll
    for (int q = 0; q < 8; ++q) acc[q] = 0.f;

    int p = p0;
    for (; p + 3 < p1; p += 4) {
        int s0 = col[p], s1 = col[p + 1], s2 = col[p + 2], s3 = col[p + 3];
        float4 r0 = *(const float4*)(hw + (size_t)s0 * 128 + j);
        float4 r1 = *(const float4*)(hw + (size_t)s1 * 128 + j);
        float4 r2 = *(const float4*)(hw + (size_t)s2 * 128 + j);
        float4 r3 = *(const float4*)(hw + (size_t)s3 * 128 + j);
        const __half2* h0 = (const __half2*)&r0;
        const __half2* h1 = (const __half2*)&r1;
        const __half2* h2 = (const __half2*)&r2;
        const __half2* h3 = (const __half2*)&r3;
#pragma unroll
        for (int q = 0; q < 4; ++q) {
            float2 f0 = __half22float2(h0[q]);
            float2 f1 = __half22float2(h1[q]);
            float2 f2 = __half22float2(h2[q]);
            float2 f3 = __half22float2(h3[q]);
            acc[2 * q + 0] += (f0.x + f1.x) + (f2.x + f3.x);
            acc[2 * q + 1] += (f0.y + f1.y) + (f2.y + f3.y);
        }
    }
    for (; p < p1; ++p) {
        int s0 = col[p];
        float4 r0 = *(const float4*)(hw + (size_t)s0 * 128 + j);
        const __half2* h0 = (const __half2*)&r0;
#pragma unroll
        for (int q = 0; q < 4; ++q) {
            float2 f0 = __half22float2(h0[q]);
            acc[2 * q + 0] += f0.x;
            acc[2 * q + 1] += f0.y;
        }
    }
    float dv = dinv[v];
    float4 bb0 = *(const float4*)(bias + j);
    float4 bb1 = *(const float4*)(bias + j + 4);
    float r[8];
    r[0] = fmaxf(acc[0] * dv + bb0.x, 0.f);
    r[1] = fmaxf(acc[1] * dv + bb0.y, 0.f);
    r[2] = fmaxf(acc[2] * dv + bb0.z, 0.f);
    r[3] = fmaxf(acc[3] * dv + bb0.w, 0.f);
    r[4] = fmaxf(acc[4] * dv + bb1.x, 0.f);
    r[5] = fmaxf(acc[5] * dv + bb1.y, 0.f);
    r[6] = fmaxf(acc[6] * dv + bb1.z, 0.f);
    r[7] = fmaxf(acc[7] * dv + bb1.w, 0.f);
    float4 pk;
    ((__half2*)&pk)[0] = __floats2half2_rn(r[0], r[1]);
    ((__half2*)&pk)[1] = __floats2half2_rn(r[2], r[3]);
    ((__half2*)&pk)[2] = __floats2half2_rn(r[4], r[5]);
    ((__half2*)&pk)[3] = __floats2half2_rn(r[6], r[7]);
    *(float4*)(out16 + (size_t)v * 128 + j) = pk;
}

// 7) graph boundary detection (batch sorted)
__global__ void boundary_kernel(const int* __restrict__ batch, int* __restrict__ start, int n) {
    int i = blockIdx.x * 256 + threadIdx.x;
    if (i >= n) return;
    int b = batch[i];
    int pb = (i > 0) ? batch[i - 1] : -1;
    if (b != pb) {
        for (int g = pb + 1; g <= b; ++g) start[g] = i;
    }
    if (i == n - 1) {
        for (int g = b + 1; g <= N_GRAPHS; ++g) start[g] = n;
    }
}

// 8) pooled mean per graph (reads fp16 h)
__global__ __launch_bounds__(256) void pool_reduce_kernel(const __half* __restrict__ h,
                                                          const int* __restrict__ start,
                                                          float* __restrict__ pooled) {
    __shared__ float part[8][128];
    int g = blockIdx.x;
    int s = start[g], e = start[g + 1];
    int tid = threadIdx.x;
    int grp = tid >> 5;
    int j = (tid & 31) * 4;
    float4 acc = make_float4(0.f, 0.f, 0.f, 0.f);
    for (int v = s + grp; v < e; v += 8) {
        float2 raw = *(const float2*)(h + (size_t)v * 128 + j);
        float2 f0 = __half22float2(((const __half2*)&raw)[0]);
        float2 f1 = __half22float2(((const __half2*)&raw)[1]);
        acc.x += f0.x; acc.y += f0.y; acc.z += f1.x; acc.w += f1.y;
    }
    *(float4*)&part[grp][j] = acc;
    __syncthreads();
    if (tid < 128) {
        float sum = 0.f;
#pragma unroll
        for (int k = 0; k < 8; ++k) sum += part[k][tid];
        int cntv = e - s; if (cntv < 1) cntv = 1;
        pooled[g * 128 + tid] = sum / (float)cntv;
    }
}

// 9) final MLP
__global__ __launch_bounds__(256) void mlp_kernel(const float* __restrict__ pooled_g,
                                                  const float* __restrict__ W1,
                                                  const float* __restrict__ b1,
                                                  const float* __restrict__ W2,
                                                  const float* __restrict__ b2,
                                                  float* __restrict__ out) {
    __shared__ float pooled[64][128];
    __shared__ float h1[64][64];
    int tid = threadIdx.x;
    for (int i = tid; i < 64 * 128; i += 256) pooled[i >> 7][i & 127] = pooled_g[i];
    __syncthreads();
    for (int i = tid; i < 64 * 64; i += 256) {
        int g = i >> 6, j = i & 63;
        float acc = b1[j];
        for (int k = 0; k < 128; ++k) acc += pooled[g][k] * W1[k * 64 + j];
        h1[g][j] = fmaxf(acc, 0.f);
    }
    __syncthreads();
    if (tid < 128) {
        int g = tid >> 1, c = tid & 1;
        float acc = b2[c];
        for (int jj = 0; jj < 64; ++jj) acc += h1[g][jj] * W2[jj * 2 + c];
        out[tid] = acc;
    }
}

// ---------------------------------------------------------------------------
extern "C" void kernel_launch(void* const* d_in, const int* in_sizes, int n_in,
                              void* d_out, int out_size, void* d_ws, size_t ws_size,
                              hipStream_t stream) {
    const float* x    = (const float*)d_in[0];
    const int*   ei   = (const int*)d_in[1];
    const int*   batch= (const int*)d_in[2];
    const float* W0   = (const float*)d_in[3];
    const float* b0   = (const float*)d_in[4];
    const float* Ws   = (const float*)d_in[5];
    const float* bs   = (const float*)d_in[6];
    const float* W1   = (const float*)d_in[7];
    const float* b1   = (const float*)d_in[8];
    const float* W2   = (const float*)d_in[9];
    const float* b2   = (const float*)d_in[10];
    float* out = (float*)d_out;

    const int n  = in_sizes[0] / HID;      // 50000
    const int E  = in_sizes[1] / 2;        // 800000
    const int EN = E + n;                  // 850000
    const int* src = ei;
    const int* dst = ei + E;
    const int nb = (n + 255) / 256;        // 196

    char* ws = (char*)d_ws;
    size_t off = 0;
    auto alloc = [&](size_t bytes) { void* p = ws + off; off = (off + bytes + 255) & ~(size_t)255; return p; };
    __half* h16    = (__half*)alloc((size_t)n * HID * 2);   // h / x16 (fp16)
    __half* hw16   = (__half*)alloc((size_t)n * HID * 2);   // gemm output (fp16)
    float*  dinv   = (float*) alloc((size_t)n * 4);
    int*    row_ptr= (int*)   alloc((size_t)(n + 1) * 4);
    int*    cursor = (int*)   alloc((size_t)n * 4);
    int*    deg    = (int*)   alloc((size_t)n * 4);
    int*    col    = (int*)   alloc((size_t)EN * 4);
    int*    bsum   = (int*)   alloc((size_t)nb * 4);
    int*    boff   = (int*)   alloc((size_t)nb * 4);
    int*    gstart = (int*)   alloc((N_GRAPHS + 1) * 4);
    float*  pooled = (float*) alloc(N_GRAPHS * 128 * 4);
    (void)ws_size; (void)n_in; (void)out_size;

    // --- build normalized CSR + fp16 input ---
    init_deg_kernel<<<nb, 256, 0, stream>>>(deg, n);
    count_kernel<<<(E + 255) / 256, 256, 0, stream>>>(dst, deg, E);
    scan_partial_kernel<<<nb, 256, 0, stream>>>(deg, bsum, n);
    scan_bsum_kernel<<<1, 256, 0, stream>>>(bsum, boff, row_ptr, nb, n);
    scan_emit_kernel<<<nb, 256, 0, stream>>>(deg, boff, row_ptr, cursor, dinv, n);
    fill_kernel<<<(EN + 255) / 256, 256, 0, stream>>>(src, dst, cursor, col, E, EN);
    boundary_kernel<<<nb, 256, 0, stream>>>(batch, gstart, n);
    cvt_kernel<<<(n * HID / 8 + 255) / 256, 256, 0, stream>>>(x, h16, n * HID / 8);

    const int gemm_grid = (n + 63) / 64;    // 782
    const int node_grid = (n + 15) / 16;    // 3125

    // --- layer 0 ---
    gemm_mfma_kernel<<<gemm_grid, 256, 0, stream>>>(h16, W0, dinv, hw16, n);
    aggregate_kernel<<<node_grid, 256, 0, stream>>>(hw16, row_ptr, col, dinv, b0, h16, n);
    // --- layers 1..3 ---
    for (int l = 0; l < 3; ++l) {
        gemm_mfma_kernel<<<gemm_grid, 256, 0, stream>>>(h16, Ws + (size_t)l * HID * HID, dinv, hw16, n);
        aggregate_kernel<<<node_grid, 256, 0, stream>>>(hw16, row_ptr, col, dinv, bs + (size_t)l * HID, h16, n);
    }

    // --- pooling + MLP ---
    pool_reduce_kernel<<<N_GRAPHS, 256, 0, stream>>>(h16, gstart, pooled);
    mlp_kernel<<<1, 256, 0, stream>>>(pooled, W1, b1, W2, b2, out);
}

// Round 13
// 446.537 us; speedup vs baseline: 1.1444x; 1.0342x over previous
//
#include <hip/hip_runtime.h>
#include <hip/hip_bf16.h>
#include <hip/hip_fp16.h>

#define HID 128
#define N_GRAPHS 64

typedef _Float16 h8 __attribute__((ext_vector_type(8)));
typedef float f4 __attribute__((ext_vector_type(4)));

// ---------------------------------------------------------------------------
// 1) degree init (self-loop counts as 1)
__global__ void init_deg_kernel(int* __restrict__ deg, int n) {
    int i = blockIdx.x * 256 + threadIdx.x;
    if (i < n) deg[i] = 1;
}

// 2) count in-degrees
__global__ void count_kernel(const int* __restrict__ dst, int* __restrict__ deg, int E) {
    int e = blockIdx.x * 256 + threadIdx.x;
    if (e < E) atomicAdd(&deg[dst[e]], 1);
}

// 3a) per-block partial sums of deg
__global__ __launch_bounds__(256) void scan_partial_kernel(const int* __restrict__ deg,
                                                           int* __restrict__ bsum, int n) {
    __shared__ int red[256];
    int t = threadIdx.x;
    int i = blockIdx.x * 256 + t;
    red[t] = (i < n) ? deg[i] : 0;
    __syncthreads();
#pragma unroll
    for (int s = 128; s > 0; s >>= 1) {
        if (t < s) red[t] += red[t + s];
        __syncthreads();
    }
    if (t == 0) bsum[blockIdx.x] = red[0];
}

// 3b) single-block exclusive scan of block sums (nb <= 256)
__global__ __launch_bounds__(256) void scan_bsum_kernel(const int* __restrict__ bsum,
                                                        int* __restrict__ boff,
                                                        int* __restrict__ row_ptr,
                                                        int nb, int n) {
    __shared__ int arr[256];
    int t = threadIdx.x;
    int own = (t < nb) ? bsum[t] : 0;
    arr[t] = own;
    __syncthreads();
#pragma unroll
    for (int off = 1; off < 256; off <<= 1) {
        int v = arr[t];
        int add = (t >= off) ? arr[t - off] : 0;
        __syncthreads();
        arr[t] = v + add;
        __syncthreads();
    }
    if (t < nb) boff[t] = arr[t] - own;
    if (t == 255) row_ptr[n] = arr[255];
}

// 3c) emit row_ptr/cursor/dinv
__global__ __launch_bounds__(256) void scan_emit_kernel(const int* __restrict__ deg,
                                                        const int* __restrict__ boff,
                                                        int* __restrict__ row_ptr,
                                                        int* __restrict__ cursor,
                                                        float* __restrict__ dinv, int n) {
    __shared__ int arr[256];
    int t = threadIdx.x;
    int i = blockIdx.x * 256 + t;
    int d = (i < n) ? deg[i] : 0;
    arr[t] = d;
    __syncthreads();
#pragma unroll
    for (int off = 1; off < 256; off <<= 1) {
        int v = arr[t];
        int add = (t >= off) ? arr[t - off] : 0;
        __syncthreads();
        arr[t] = v + add;
        __syncthreads();
    }
    if (i < n) {
        int pos = boff[blockIdx.x] + arr[t] - d;
        row_ptr[i] = pos;
        cursor[i] = pos;
        dinv[i] = rsqrtf((float)d);
    }
}

// 4) fill CSR columns — dst-range partitioned with XCD affinity.
//    Blocks with blockIdx&7 == r (co-resident on XCD r via round-robin mapping)
//    handle only dst in range r, so each range's ~425KB col region stays in one
//    L2 and the ~16 writes per 64B line coalesce before writeback.
__global__ __launch_bounds__(256) void fill_kernel(const int* __restrict__ src,
                                                   const int* __restrict__ dst,
                                                   int* __restrict__ cursor,
                                                   int* __restrict__ col,
                                                   int E, int n) {
    int r = blockIdx.x & 7;
    int sub = blockIdx.x >> 3;
    int nsub = gridDim.x >> 3;
    int rw = (n + 7) / 8;
    int lo = r * rw;
    int hi = lo + rw; if (hi > n) hi = n;
    int t = threadIdx.x;
    // edges in this dst range
    for (int e = sub * 256 + t; e < E; e += nsub * 256) {
        int d = dst[e];
        if (d >= lo && d < hi) {
            int pos = atomicAdd(&cursor[d], 1);
            col[pos] = src[e];
        }
    }
    // self-loops for this range
    for (int v = lo + sub * 256 + t; v < hi; v += nsub * 256) {
        int pos = atomicAdd(&cursor[v], 1);
        col[pos] = v;
    }
}

// 4b) fp32 -> fp16 convert (8 elems/thread)
__global__ void cvt_kernel(const float* __restrict__ in, __half* __restrict__ out, int total8) {
    int i = blockIdx.x * 256 + threadIdx.x;
    if (i >= total8) return;
    float4 v0 = *(const float4*)(in + (size_t)i * 8);
    float4 v1 = *(const float4*)(in + (size_t)i * 8 + 4);
    __half2 p0 = __floats2half2_rn(v0.x, v0.y);
    __half2 p1 = __floats2half2_rn(v0.z, v0.w);
    __half2 p2 = __floats2half2_rn(v1.x, v1.y);
    __half2 p3 = __floats2half2_rn(v1.z, v1.w);
    float4 pk;
    ((__half2*)&pk)[0] = p0; ((__half2*)&pk)[1] = p1;
    ((__half2*)&pk)[2] = p2; ((__half2*)&pk)[3] = p3;
    *(float4*)(out + (size_t)i * 8) = pk;
}

// 5) MFMA GEMM: hw16[r][:] = fp16( dinv[r] * (A16[r][:] @ W) )
//    64 rows/block (4 waves x 16 rows), W^T staged fp16 in LDS [128][136].
//    A-frag: lane l holds A[row + (l&15)][8*(l>>4)..+7]
//    C-frag (m89-verified): col = l&15, row = (l>>4)*4 + reg
__global__ __launch_bounds__(256) void gemm_mfma_kernel(const __half* __restrict__ A16,
                                                        const float* __restrict__ W,
                                                        const float* __restrict__ dinv,
                                                        __half* __restrict__ out16, int M) {
    __shared__ _Float16 sWt[128][136];
    int tid = threadIdx.x;
    for (int i = tid * 4; i < 128 * 128; i += 1024) {
        int k = i >> 7, nn = i & 127;
        float4 v = *(const float4*)(W + i);
        sWt[nn + 0][k] = (_Float16)v.x;
        sWt[nn + 1][k] = (_Float16)v.y;
        sWt[nn + 2][k] = (_Float16)v.z;
        sWt[nn + 3][k] = (_Float16)v.w;
    }
    __syncthreads();

    int wave = tid >> 6;
    int lane = tid & 63;
    int l15 = lane & 15;
    int kg = lane >> 4;
    int rowb = blockIdx.x * 64 + wave * 16;
    int arow = rowb + l15;

    h8 zero;
#pragma unroll
    for (int q = 0; q < 8; ++q) zero[q] = (_Float16)0.f;

    h8 afrag[4];
    if (arow < M) {
        const h8* Av = (const h8*)(A16 + (size_t)arow * 128 + kg * 8);
#pragma unroll
        for (int kc = 0; kc < 4; ++kc) afrag[kc] = Av[kc * 4];
    } else {
#pragma unroll
        for (int kc = 0; kc < 4; ++kc) afrag[kc] = zero;
    }

    int orow0 = rowb + kg * 4;
    float dv[4];
#pragma unroll
    for (int j = 0; j < 4; ++j)
        dv[j] = (orow0 + j < M) ? dinv[orow0 + j] : 0.f;

    for (int ct = 0; ct < 8; ++ct) {
        h8 bfrag[4];
#pragma unroll
        for (int kc = 0; kc < 4; ++kc)
            bfrag[kc] = *(const h8*)&sWt[ct * 16 + l15][kc * 32 + kg * 8];
        f4 acc = {0.f, 0.f, 0.f, 0.f};
#pragma unroll
        for (int kc = 0; kc < 4; ++kc)
            acc = __builtin_amdgcn_mfma_f32_16x16x32_f16(afrag[kc], bfrag[kc], acc, 0, 0, 0);
#pragma unroll
        for (int j = 0; j < 4; ++j) {
            int r = orow0 + j;
            if (r < M)
                out16[(size_t)r * 128 + ct * 16 + l15] = __float2half(acc[j] * dv[j]);
        }
    }
}

// 6) aggregation: h16[v][:] = fp16( relu(dinv[v] * sum_{s in N(v)} hw16[s][:] + b) )
__global__ __launch_bounds__(256) void aggregate_kernel(const __half* __restrict__ hw,
                                                        const int* __restrict__ row_ptr,
                                                        const int* __restrict__ col,
                                                        const float* __restrict__ dinv,
                                                        const float* __restrict__ bias,
                                                        __half* __restrict__ out16, int n) {
    int tid = threadIdx.x;
    int v = blockIdx.x * 16 + (tid >> 4);
    if (v >= n) return;
    int j = (tid & 15) * 8;
    int p0 = row_ptr[v], p1 = row_ptr[v + 1];
    float acc[8];
#pragma unroll
    for (int q = 0; q < 8; ++q) acc[q] = 0.f;

    int p = p0;
    for (; p + 3 < p1; p += 4) {
        int s0 = col[p], s1 = col[p + 1], s2 = col[p + 2], s3 = col[p + 3];
        float4 r0 = *(const float4*)(hw + (size_t)s0 * 128 + j);
        float4 r1 = *(const float4*)(hw + (size_t)s1 * 128 + j);
        float4 r2 = *(const float4*)(hw + (size_t)s2 * 128 + j);
        float4 r3 = *(const float4*)(hw + (size_t)s3 * 128 + j);
        const __half2* h0 = (const __half2*)&r0;
        const __half2* h1 = (const __half2*)&r1;
        const __half2* h2 = (const __half2*)&r2;
        const __half2* h3 = (const __half2*)&r3;
#pragma unroll
        for (int q = 0; q < 4; ++q) {
            float2 f0 = __half22float2(h0[q]);
            float2 f1 = __half22float2(h1[q]);
            float2 f2 = __half22float2(h2[q]);
            float2 f3 = __half22float2(h3[q]);
            acc[2 * q + 0] += (f0.x + f1.x) + (f2.x + f3.x);
            acc[2 * q + 1] += (f0.y + f1.y) + (f2.y + f3.y);
        }
    }
    for (; p < p1; ++p) {
        int s0 = col[p];
        float4 r0 = *(const float4*)(hw + (size_t)s0 * 128 + j);
        const __half2* h0 = (const __half2*)&r0;
#pragma unroll
        for (int q = 0; q < 4; ++q) {
            float2 f0 = __half22float2(h0[q]);
            acc[2 * q + 0] += f0.x;
            acc[2 * q + 1] += f0.y;
        }
    }
    float dv = dinv[v];
    float4 bb0 = *(const float4*)(bias + j);
    float4 bb1 = *(const float4*)(bias + j + 4);
    float r[8];
    r[0] = fmaxf(acc[0] * dv + bb0.x, 0.f);
    r[1] = fmaxf(acc[1] * dv + bb0.y, 0.f);
    r[2] = fmaxf(acc[2] * dv + bb0.z, 0.f);
    r[3] = fmaxf(acc[3] * dv + bb0.w, 0.f);
    r[4] = fmaxf(acc[4] * dv + bb1.x, 0.f);
    r[5] = fmaxf(acc[5] * dv + bb1.y, 0.f);
    r[6] = fmaxf(acc[6] * dv + bb1.z, 0.f);
    r[7] = fmaxf(acc[7] * dv + bb1.w, 0.f);
    float4 pk;
    ((__half2*)&pk)[0] = __floats2half2_rn(r[0], r[1]);
    ((__half2*)&pk)[1] = __floats2half2_rn(r[2], r[3]);
    ((__half2*)&pk)[2] = __floats2half2_rn(r[4], r[5]);
    ((__half2*)&pk)[3] = __floats2half2_rn(r[6], r[7]);
    *(float4*)(out16 + (size_t)v * 128 + j) = pk;
}

// 7) graph boundary detection (batch sorted)
__global__ void boundary_kernel(const int* __restrict__ batch, int* __restrict__ start, int n) {
    int i = blockIdx.x * 256 + threadIdx.x;
    if (i >= n) return;
    int b = batch[i];
    int pb = (i > 0) ? batch[i - 1] : -1;
    if (b != pb) {
        for (int g = pb + 1; g <= b; ++g) start[g] = i;
    }
    if (i == n - 1) {
        for (int g = b + 1; g <= N_GRAPHS; ++g) start[g] = n;
    }
}

// 8) pooled mean per graph (reads fp16 h)
__global__ __launch_bounds__(256) void pool_reduce_kernel(const __half* __restrict__ h,
                                                          const int* __restrict__ start,
                                                          float* __restrict__ pooled) {
    __shared__ float part[8][128];
    int g = blockIdx.x;
    int s = start[g], e = start[g + 1];
    int tid = threadIdx.x;
    int grp = tid >> 5;
    int j = (tid & 31) * 4;
    float4 acc = make_float4(0.f, 0.f, 0.f, 0.f);
    for (int v = s + grp; v < e; v += 8) {
        float2 raw = *(const float2*)(h + (size_t)v * 128 + j);
        float2 f0 = __half22float2(((const __half2*)&raw)[0]);
        float2 f1 = __half22float2(((const __half2*)&raw)[1]);
        acc.x += f0.x; acc.y += f0.y; acc.z += f1.x; acc.w += f1.y;
    }
    *(float4*)&part[grp][j] = acc;
    __syncthreads();
    if (tid < 128) {
        float sum = 0.f;
#pragma unroll
        for (int k = 0; k < 8; ++k) sum += part[k][tid];
        int cntv = e - s; if (cntv < 1) cntv = 1;
        pooled[g * 128 + tid] = sum / (float)cntv;
    }
}

// 9) final MLP
__global__ __launch_bounds__(256) void mlp_kernel(const float* __restrict__ pooled_g,
                                                  const float* __restrict__ W1,
                                                  const float* __restrict__ b1,
                                                  const float* __restrict__ W2,
                                                  const float* __restrict__ b2,
                                                  float* __restrict__ out) {
    __shared__ float pooled[64][128];
    __shared__ float h1[64][64];
    int tid = threadIdx.x;
    for (int i = tid; i < 64 * 128; i += 256) pooled[i >> 7][i & 127] = pooled_g[i];
    __syncthreads();
    for (int i = tid; i < 64 * 64; i += 256) {
        int g = i >> 6, j = i & 63;
        float acc = b1[j];
        for (int k = 0; k < 128; ++k) acc += pooled[g][k] * W1[k * 64 + j];
        h1[g][j] = fmaxf(acc, 0.f);
    }
    __syncthreads();
    if (tid < 128) {
        int g = tid >> 1, c = tid & 1;
        float acc = b2[c];
        for (int jj = 0; jj < 64; ++jj) acc += h1[g][jj] * W2[jj * 2 + c];
        out[tid] = acc;
    }
}

// ---------------------------------------------------------------------------
extern "C" void kernel_launch(void* const* d_in, const int* in_sizes, int n_in,
                              void* d_out, int out_size, void* d_ws, size_t ws_size,
                              hipStream_t stream) {
    const float* x    = (const float*)d_in[0];
    const int*   ei   = (const int*)d_in[1];
    const int*   batch= (const int*)d_in[2];
    const float* W0   = (const float*)d_in[3];
    const float* b0   = (const float*)d_in[4];
    const float* Ws   = (const float*)d_in[5];
    const float* bs   = (const float*)d_in[6];
    const float* W1   = (const float*)d_in[7];
    const float* b1   = (const float*)d_in[8];
    const float* W2   = (const float*)d_in[9];
    const float* b2   = (const float*)d_in[10];
    float* out = (float*)d_out;

    const int n  = in_sizes[0] / HID;      // 50000
    const int E  = in_sizes[1] / 2;        // 800000
    const int EN = E + n;                  // 850000
    const int* src = ei;
    const int* dst = ei + E;
    const int nb = (n + 255) / 256;        // 196

    char* ws = (char*)d_ws;
    size_t off = 0;
    auto alloc = [&](size_t bytes) { void* p = ws + off; off = (off + bytes + 255) & ~(size_t)255; return p; };
    __half* h16    = (__half*)alloc((size_t)n * HID * 2);   // h / x16 (fp16)
    __half* hw16   = (__half*)alloc((size_t)n * HID * 2);   // gemm output (fp16)
    float*  dinv   = (float*) alloc((size_t)n * 4);
    int*    row_ptr= (int*)   alloc((size_t)(n + 1) * 4);
    int*    cursor = (int*)   alloc((size_t)n * 4);
    int*    deg    = (int*)   alloc((size_t)n * 4);
    int*    col    = (int*)   alloc((size_t)EN * 4);
    int*    bsum   = (int*)   alloc((size_t)nb * 4);
    int*    boff   = (int*)   alloc((size_t)nb * 4);
    int*    gstart = (int*)   alloc((N_GRAPHS + 1) * 4);
    float*  pooled = (float*) alloc(N_GRAPHS * 128 * 4);
    (void)ws_size; (void)n_in; (void)out_size;

    // --- build normalized CSR + fp16 input ---
    init_deg_kernel<<<nb, 256, 0, stream>>>(deg, n);
    count_kernel<<<(E + 255) / 256, 256, 0, stream>>>(dst, deg, E);
    scan_partial_kernel<<<nb, 256, 0, stream>>>(deg, bsum, n);
    scan_bsum_kernel<<<1, 256, 0, stream>>>(bsum, boff, row_ptr, nb, n);
    scan_emit_kernel<<<nb, 256, 0, stream>>>(deg, boff, row_ptr, cursor, dinv, n);
    fill_kernel<<<512, 256, 0, stream>>>(src, dst, cursor, col, E, n);
    boundary_kernel<<<nb, 256, 0, stream>>>(batch, gstart, n);
    cvt_kernel<<<(n * HID / 8 + 255) / 256, 256, 0, stream>>>(x, h16, n * HID / 8);

    const int gemm_grid = (n + 63) / 64;    // 782
    const int node_grid = (n + 15) / 16;    // 3125

    // --- layer 0 ---
    gemm_mfma_kernel<<<gemm_grid, 256, 0, stream>>>(h16, W0, dinv, hw16, n);
    aggregate_kernel<<<node_grid, 256, 0, stream>>>(hw16, row_ptr, col, dinv, b0, h16, n);
    // --- layers 1..3 ---
    for (int l = 0; l < 3; ++l) {
        gemm_mfma_kernel<<<gemm_grid, 256, 0, stream>>>(h16, Ws + (size_t)l * HID * HID, dinv, hw16, n);
        aggregate_kernel<<<node_grid, 256, 0, stream>>>(hw16, row_ptr, col, dinv, bs + (size_t)l * HID, h16, n);
    }

    // --- pooling + MLP ---
    pool_reduce_kernel<<<N_GRAPHS, 256, 0, stream>>>(h16, gstart, pooled);
    mlp_kernel<<<1, 256, 0, stream>>>(pooled, W1, b1, W2, b2, out);
}

// Round 14
// 416.766 us; speedup vs baseline: 1.2262x; 1.0714x over previous
//
#include <hip/hip_runtime.h>
#include <hip/hip_bf16.h>
#include <hip/hip_fp16.h>

#define HID 128
#define N_GRAPHS 64

typedef _Float16 h8 __attribute__((ext_vector_type(8)));
typedef float f4 __attribute__((ext_vector_type(4)));

// ---------------------------------------------------------------------------
// 1) zero edge-count array (self-loop folded in as deg+1 at scan time)
__global__ void init_deg_kernel(int* __restrict__ deg, int n) {
    int i = blockIdx.x * 256 + threadIdx.x;
    if (i < n) deg[i] = 0;
}

// 2) count in-degrees — XCD-range partitioned: blocks with blockIdx&7==r are
//    co-resident on XCD r; they only touch deg[lo..hi) (~25KB), which stays in
//    that XCD's L2 so the atomic traffic never crosses the fabric.
__global__ __launch_bounds__(256) void count_kernel(const int* __restrict__ dst,
                                                    int* __restrict__ deg, int E, int n) {
    int r = blockIdx.x & 7;
    int sub = blockIdx.x >> 3;
    int nsub = gridDim.x >> 3;
    int rw = (n + 7) / 8;
    int lo = r * rw;
    int hi = lo + rw; if (hi > n) hi = n;
    for (int e = sub * 256 + threadIdx.x; e < E; e += nsub * 256) {
        int d = dst[e];
        if (d >= lo && d < hi) atomicAdd(&deg[d], 1);
    }
}

// 3a) per-block partial sums of (deg+1)
__global__ __launch_bounds__(256) void scan_partial_kernel(const int* __restrict__ deg,
                                                           int* __restrict__ bsum, int n) {
    __shared__ int red[256];
    int t = threadIdx.x;
    int i = blockIdx.x * 256 + t;
    red[t] = (i < n) ? deg[i] + 1 : 0;
    __syncthreads();
#pragma unroll
    for (int s = 128; s > 0; s >>= 1) {
        if (t < s) red[t] += red[t + s];
        __syncthreads();
    }
    if (t == 0) bsum[blockIdx.x] = red[0];
}

// 3b) single-block exclusive scan of block sums (nb <= 256)
__global__ __launch_bounds__(256) void scan_bsum_kernel(const int* __restrict__ bsum,
                                                        int* __restrict__ boff,
                                                        int* __restrict__ row_ptr,
                                                        int nb, int n) {
    __shared__ int arr[256];
    int t = threadIdx.x;
    int own = (t < nb) ? bsum[t] : 0;
    arr[t] = own;
    __syncthreads();
#pragma unroll
    for (int off = 1; off < 256; off <<= 1) {
        int v = arr[t];
        int add = (t >= off) ? arr[t - off] : 0;
        __syncthreads();
        arr[t] = v + add;
        __syncthreads();
    }
    if (t < nb) boff[t] = arr[t] - own;
    if (t == 255) row_ptr[n] = arr[255];
}

// 3c) emit row_ptr/cursor/dinv  (degree incl. self-loop = deg+1)
__global__ __launch_bounds__(256) void scan_emit_kernel(const int* __restrict__ deg,
                                                        const int* __restrict__ boff,
                                                        int* __restrict__ row_ptr,
                                                        int* __restrict__ cursor,
                                                        float* __restrict__ dinv, int n) {
    __shared__ int arr[256];
    int t = threadIdx.x;
    int i = blockIdx.x * 256 + t;
    int d = (i < n) ? deg[i] + 1 : 0;
    arr[t] = d;
    __syncthreads();
#pragma unroll
    for (int off = 1; off < 256; off <<= 1) {
        int v = arr[t];
        int add = (t >= off) ? arr[t - off] : 0;
        __syncthreads();
        arr[t] = v + add;
        __syncthreads();
    }
    if (i < n) {
        int pos = boff[blockIdx.x] + arr[t] - d;
        row_ptr[i] = pos;
        cursor[i] = pos;
        dinv[i] = rsqrtf((float)d);
    }
}

// 4) fill CSR columns — dst-range partitioned with XCD affinity (grid 2048).
__global__ __launch_bounds__(256) void fill_kernel(const int* __restrict__ src,
                                                   const int* __restrict__ dst,
                                                   int* __restrict__ cursor,
                                                   int* __restrict__ col,
                                                   int E, int n) {
    int r = blockIdx.x & 7;
    int sub = blockIdx.x >> 3;
    int nsub = gridDim.x >> 3;
    int rw = (n + 7) / 8;
    int lo = r * rw;
    int hi = lo + rw; if (hi > n) hi = n;
    int t = threadIdx.x;
    for (int e = sub * 256 + t; e < E; e += nsub * 256) {
        int d = dst[e];
        if (d >= lo && d < hi) {
            int pos = atomicAdd(&cursor[d], 1);
            col[pos] = src[e];
        }
    }
    for (int v = lo + sub * 256 + t; v < hi; v += nsub * 256) {
        int pos = atomicAdd(&cursor[v], 1);
        col[pos] = v;
    }
}

// 4b) fp32 -> fp16 convert (8 elems/thread)
__global__ void cvt_kernel(const float* __restrict__ in, __half* __restrict__ out, int total8) {
    int i = blockIdx.x * 256 + threadIdx.x;
    if (i >= total8) return;
    float4 v0 = *(const float4*)(in + (size_t)i * 8);
    float4 v1 = *(const float4*)(in + (size_t)i * 8 + 4);
    __half2 p0 = __floats2half2_rn(v0.x, v0.y);
    __half2 p1 = __floats2half2_rn(v0.z, v0.w);
    __half2 p2 = __floats2half2_rn(v1.x, v1.y);
    __half2 p3 = __floats2half2_rn(v1.z, v1.w);
    float4 pk;
    ((__half2*)&pk)[0] = p0; ((__half2*)&pk)[1] = p1;
    ((__half2*)&pk)[2] = p2; ((__half2*)&pk)[3] = p3;
    *(float4*)(out + (size_t)i * 8) = pk;
}

// 5) MFMA GEMM: hw16[r][:] = fp16( dinv[r] * (A16[r][:] @ W) )
//    128 rows/block (4 waves x 2x16 rows) — halves per-block W staging vs 64.
//    W^T staged fp16 in LDS [128][136]; bfrag reused for both row groups.
//    A-frag: lane l holds A[row + (l&15)][8*(l>>4)..+7]
//    C-frag (m89-verified): col = l&15, row = (l>>4)*4 + reg
__global__ __launch_bounds__(256) void gemm_mfma_kernel(const __half* __restrict__ A16,
                                                        const float* __restrict__ W,
                                                        const float* __restrict__ dinv,
                                                        __half* __restrict__ out16, int M) {
    __shared__ _Float16 sWt[128][136];
    int tid = threadIdx.x;
    for (int i = tid * 4; i < 128 * 128; i += 1024) {
        int k = i >> 7, nn = i & 127;
        float4 v = *(const float4*)(W + i);
        sWt[nn + 0][k] = (_Float16)v.x;
        sWt[nn + 1][k] = (_Float16)v.y;
        sWt[nn + 2][k] = (_Float16)v.z;
        sWt[nn + 3][k] = (_Float16)v.w;
    }
    __syncthreads();

    int wave = tid >> 6;
    int lane = tid & 63;
    int l15 = lane & 15;
    int kg = lane >> 4;
    int rowb = blockIdx.x * 128 + wave * 32;     // this wave: rows [rowb, rowb+32)
    int arowA = rowb + l15;
    int arowB = rowb + 16 + l15;

    h8 zero;
#pragma unroll
    for (int q = 0; q < 8; ++q) zero[q] = (_Float16)0.f;

    h8 afragA[4], afragB[4];
    if (arowA < M) {
        const h8* Av = (const h8*)(A16 + (size_t)arowA * 128 + kg * 8);
#pragma unroll
        for (int kc = 0; kc < 4; ++kc) afragA[kc] = Av[kc * 4];
    } else {
#pragma unroll
        for (int kc = 0; kc < 4; ++kc) afragA[kc] = zero;
    }
    if (arowB < M) {
        const h8* Av = (const h8*)(A16 + (size_t)arowB * 128 + kg * 8);
#pragma unroll
        for (int kc = 0; kc < 4; ++kc) afragB[kc] = Av[kc * 4];
    } else {
#pragma unroll
        for (int kc = 0; kc < 4; ++kc) afragB[kc] = zero;
    }

    int orowA = rowb + kg * 4;
    int orowB = rowb + 16 + kg * 4;
    float dvA[4], dvB[4];
#pragma unroll
    for (int j = 0; j < 4; ++j) {
        dvA[j] = (orowA + j < M) ? dinv[orowA + j] : 0.f;
        dvB[j] = (orowB + j < M) ? dinv[orowB + j] : 0.f;
    }

    for (int ct = 0; ct < 8; ++ct) {
        h8 bfrag[4];
#pragma unroll
        for (int kc = 0; kc < 4; ++kc)
            bfrag[kc] = *(const h8*)&sWt[ct * 16 + l15][kc * 32 + kg * 8];
        f4 accA = {0.f, 0.f, 0.f, 0.f};
        f4 accB = {0.f, 0.f, 0.f, 0.f};
#pragma unroll
        for (int kc = 0; kc < 4; ++kc) {
            accA = __builtin_amdgcn_mfma_f32_16x16x32_f16(afragA[kc], bfrag[kc], accA, 0, 0, 0);
            accB = __builtin_amdgcn_mfma_f32_16x16x32_f16(afragB[kc], bfrag[kc], accB, 0, 0, 0);
        }
#pragma unroll
        for (int j = 0; j < 4; ++j) {
            int rA = orowA + j;
            if (rA < M)
                out16[(size_t)rA * 128 + ct * 16 + l15] = __float2half(accA[j] * dvA[j]);
            int rB = orowB + j;
            if (rB < M)
                out16[(size_t)rB * 128 + ct * 16 + l15] = __float2half(accB[j] * dvB[j]);
        }
    }
}

// 6) aggregation: h16[v][:] = fp16( relu(dinv[v] * sum_{s in N(v)} hw16[s][:] + b) )
__global__ __launch_bounds__(256) void aggregate_kernel(const __half* __restrict__ hw,
                                                        const int* __restrict__ row_ptr,
                                                        const int* __restrict__ col,
                                                        const float* __restrict__ dinv,
                                                        const float* __restrict__ bias,
                                                        __half* __restrict__ out16, int n) {
    int tid = threadIdx.x;
    int v = blockIdx.x * 16 + (tid >> 4);
    if (v >= n) return;
    int j = (tid & 15) * 8;
    int p0 = row_ptr[v], p1 = row_ptr[v + 1];
    float acc[8];
#pragma unroll
    for (int q = 0; q < 8; ++q) acc[q] = 0.f;

    int p = p0;
    for (; p + 3 < p1; p += 4) {
        int s0 = col[p], s1 = col[p + 1], s2 = col[p + 2], s3 = col[p + 3];
        float4 r0 = *(const float4*)(hw + (size_t)s0 * 128 + j);
        float4 r1 = *(const float4*)(hw + (size_t)s1 * 128 + j);
        float4 r2 = *(const float4*)(hw + (size_t)s2 * 128 + j);
        float4 r3 = *(const float4*)(hw + (size_t)s3 * 128 + j);
        const __half2* h0 = (const __half2*)&r0;
        const __half2* h1 = (const __half2*)&r1;
        const __half2* h2 = (const __half2*)&r2;
        const __half2* h3 = (const __half2*)&r3;
#pragma unroll
        for (int q = 0; q < 4; ++q) {
            float2 f0 = __half22float2(h0[q]);
            float2 f1 = __half22float2(h1[q]);
            float2 f2 = __half22float2(h2[q]);
            float2 f3 = __half22float2(h3[q]);
            acc[2 * q + 0] += (f0.x + f1.x) + (f2.x + f3.x);
            acc[2 * q + 1] += (f0.y + f1.y) + (f2.y + f3.y);
        }
    }
    for (; p < p1; ++p) {
        int s0 = col[p];
        float4 r0 = *(const float4*)(hw + (size_t)s0 * 128 + j);
        const __half2* h0 = (const __half2*)&r0;
#pragma unroll
        for (int q = 0; q < 4; ++q) {
            float2 f0 = __half22float2(h0[q]);
            acc[2 * q + 0] += f0.x;
            acc[2 * q + 1] += f0.y;
        }
    }
    float dv = dinv[v];
    float4 bb0 = *(const float4*)(bias + j);
    float4 bb1 = *(const float4*)(bias + j + 4);
    float r[8];
    r[0] = fmaxf(acc[0] * dv + bb0.x, 0.f);
    r[1] = fmaxf(acc[1] * dv + bb0.y, 0.f);
    r[2] = fmaxf(acc[2] * dv + bb0.z, 0.f);
    r[3] = fmaxf(acc[3] * dv + bb0.w, 0.f);
    r[4] = fmaxf(acc[4] * dv + bb1.x, 0.f);
    r[5] = fmaxf(acc[5] * dv + bb1.y, 0.f);
    r[6] = fmaxf(acc[6] * dv + bb1.z, 0.f);
    r[7] = fmaxf(acc[7] * dv + bb1.w, 0.f);
    float4 pk;
    ((__half2*)&pk)[0] = __floats2half2_rn(r[0], r[1]);
    ((__half2*)&pk)[1] = __floats2half2_rn(r[2], r[3]);
    ((__half2*)&pk)[2] = __floats2half2_rn(r[4], r[5]);
    ((__half2*)&pk)[3] = __floats2half2_rn(r[6], r[7]);
    *(float4*)(out16 + (size_t)v * 128 + j) = pk;
}

// 7) graph boundary detection (batch sorted)
__global__ void boundary_kernel(const int* __restrict__ batch, int* __restrict__ start, int n) {
    int i = blockIdx.x * 256 + threadIdx.x;
    if (i >= n) return;
    int b = batch[i];
    int pb = (i > 0) ? batch[i - 1] : -1;
    if (b != pb) {
        for (int g = pb + 1; g <= b; ++g) start[g] = i;
    }
    if (i == n - 1) {
        for (int g = b + 1; g <= N_GRAPHS; ++g) start[g] = n;
    }
}

// 8) pooled mean per graph (reads fp16 h)
__global__ __launch_bounds__(256) void pool_reduce_kernel(const __half* __restrict__ h,
                                                          const int* __restrict__ start,
                                                          float* __restrict__ pooled) {
    __shared__ float part[8][128];
    int g = blockIdx.x;
    int s = start[g], e = start[g + 1];
    int tid = threadIdx.x;
    int grp = tid >> 5;
    int j = (tid & 31) * 4;
    float4 acc = make_float4(0.f, 0.f, 0.f, 0.f);
    for (int v = s + grp; v < e; v += 8) {
        float2 raw = *(const float2*)(h + (size_t)v * 128 + j);
        float2 f0 = __half22float2(((const __half2*)&raw)[0]);
        float2 f1 = __half22float2(((const __half2*)&raw)[1]);
        acc.x += f0.x; acc.y += f0.y; acc.z += f1.x; acc.w += f1.y;
    }
    *(float4*)&part[grp][j] = acc;
    __syncthreads();
    if (tid < 128) {
        float sum = 0.f;
#pragma unroll
        for (int k = 0; k < 8; ++k) sum += part[k][tid];
        int cntv = e - s; if (cntv < 1) cntv = 1;
        pooled[g * 128 + tid] = sum / (float)cntv;
    }
}

// 9) final MLP
__global__ __launch_bounds__(256) void mlp_kernel(const float* __restrict__ pooled_g,
                                                  const float* __restrict__ W1,
                                                  const float* __restrict__ b1,
                                                  const float* __restrict__ W2,
                                                  const float* __restrict__ b2,
                                                  float* __restrict__ out) {
    __shared__ float pooled[64][128];
    __shared__ float h1[64][64];
    int tid = threadIdx.x;
    for (int i = tid; i < 64 * 128; i += 256) pooled[i >> 7][i & 127] = pooled_g[i];
    __syncthreads();
    for (int i = tid; i < 64 * 64; i += 256) {
        int g = i >> 6, j = i & 63;
        float acc = b1[j];
        for (int k = 0; k < 128; ++k) acc += pooled[g][k] * W1[k * 64 + j];
        h1[g][j] = fmaxf(acc, 0.f);
    }
    __syncthreads();
    if (tid < 128) {
        int g = tid >> 1, c = tid & 1;
        float acc = b2[c];
        for (int jj = 0; jj < 64; ++jj) acc += h1[g][jj] * W2[jj * 2 + c];
        out[tid] = acc;
    }
}

// ---------------------------------------------------------------------------
extern "C" void kernel_launch(void* const* d_in, const int* in_sizes, int n_in,
                              void* d_out, int out_size, void* d_ws, size_t ws_size,
                              hipStream_t stream) {
    const float* x    = (const float*)d_in[0];
    const int*   ei   = (const int*)d_in[1];
    const int*   batch= (const int*)d_in[2];
    const float* W0   = (const float*)d_in[3];
    const float* b0   = (const float*)d_in[4];
    const float* Ws   = (const float*)d_in[5];
    const float* bs   = (const float*)d_in[6];
    const float* W1   = (const float*)d_in[7];
    const float* b1   = (const float*)d_in[8];
    const float* W2   = (const float*)d_in[9];
    const float* b2   = (const float*)d_in[10];
    float* out = (float*)d_out;

    const int n  = in_sizes[0] / HID;      // 50000
    const int E  = in_sizes[1] / 2;        // 800000
    const int* src = ei;
    const int* dst = ei + E;
    const int nb = (n + 255) / 256;        // 196
    const int EN = E + n;

    char* ws = (char*)d_ws;
    size_t off = 0;
    auto alloc = [&](size_t bytes) { void* p = ws + off; off = (off + bytes + 255) & ~(size_t)255; return p; };
    __half* h16    = (__half*)alloc((size_t)n * HID * 2);   // h / x16 (fp16)
    __half* hw16   = (__half*)alloc((size_t)n * HID * 2);   // gemm output (fp16)
    float*  dinv   = (float*) alloc((size_t)n * 4);
    int*    row_ptr= (int*)   alloc((size_t)(n + 1) * 4);
    int*    cursor = (int*)   alloc((size_t)n * 4);
    int*    deg    = (int*)   alloc((size_t)n * 4);
    int*    col    = (int*)   alloc((size_t)EN * 4);
    int*    bsum   = (int*)   alloc((size_t)nb * 4);
    int*    boff   = (int*)   alloc((size_t)nb * 4);
    int*    gstart = (int*)   alloc((N_GRAPHS + 1) * 4);
    float*  pooled = (float*) alloc(N_GRAPHS * 128 * 4);
    (void)ws_size; (void)n_in; (void)out_size;

    // --- build normalized CSR + fp16 input ---
    init_deg_kernel<<<nb, 256, 0, stream>>>(deg, n);
    count_kernel<<<2048, 256, 0, stream>>>(dst, deg, E, n);
    scan_partial_kernel<<<nb, 256, 0, stream>>>(deg, bsum, n);
    scan_bsum_kernel<<<1, 256, 0, stream>>>(bsum, boff, row_ptr, nb, n);
    scan_emit_kernel<<<nb, 256, 0, stream>>>(deg, boff, row_ptr, cursor, dinv, n);
    fill_kernel<<<2048, 256, 0, stream>>>(src, dst, cursor, col, E, n);
    boundary_kernel<<<nb, 256, 0, stream>>>(batch, gstart, n);
    cvt_kernel<<<(n * HID / 8 + 255) / 256, 256, 0, stream>>>(x, h16, n * HID / 8);

    const int gemm_grid = (n + 127) / 128;  // 391
    const int node_grid = (n + 15) / 16;    // 3125

    // --- layer 0 ---
    gemm_mfma_kernel<<<gemm_grid, 256, 0, stream>>>(h16, W0, dinv, hw16, n);
    aggregate_kernel<<<node_grid, 256, 0, stream>>>(hw16, row_ptr, col, dinv, b0, h16, n);
    // --- layers 1..3 ---
    for (int l = 0; l < 3; ++l) {
        gemm_mfma_kernel<<<gemm_grid, 256, 0, stream>>>(h16, Ws + (size_t)l * HID * HID, dinv, hw16, n);
        aggregate_kernel<<<node_grid, 256, 0, stream>>>(hw16, row_ptr, col, dinv, bs + (size_t)l * HID, h16, n);
    }

    // --- pooling + MLP ---
    pool_reduce_kernel<<<N_GRAPHS, 256, 0, stream>>>(h16, gstart, pooled);
    mlp_kernel<<<1, 256, 0, stream>>>(pooled, W1, b1, W2, b2, out);
}